// Round 1
// baseline (7826.509 us; speedup 1.0000x reference)
//
#include <hip/hip_runtime.h>
#include <hip/hip_fp16.h>
#include <cstdint>
#include <cstddef>

typedef _Float16 f16;
typedef _Float16 f16x8 __attribute__((ext_vector_type(8)));
typedef _Float16 f16x4 __attribute__((ext_vector_type(4)));
typedef float    f32x4 __attribute__((ext_vector_type(4)));
typedef unsigned int u32;

#define NB 128     // batch
#define NT 64      // trg seq len
#define NH 768     // hidden
#define NV 32000   // vocab
#define NG 3072    // 4*NH

__device__ __forceinline__ void gld_lds16(const void* gp, void* lp) {
  __builtin_amdgcn_global_load_lds((const __attribute__((address_space(1))) u32*)gp,
                                   (__attribute__((address_space(3))) u32*)lp, 16, 0, 0);
}
__device__ __forceinline__ float sigm(float x) { return 1.f / (1.f + __expf(-x)); }
__device__ __forceinline__ float tanh_fast(float x) { return 1.f - 2.f / (__expf(2.f * x) + 1.f); }

// ---------------- prep kernels ----------------

__global__ void cvt4(const float4* __restrict__ s, f16x4* __restrict__ d, int n4) {
  int i = blockIdx.x * blockDim.x + threadIdx.x;
  if (i < n4) {
    float4 v = s[i];
    f16x4 o; o[0] = (f16)v.x; o[1] = (f16)v.y; o[2] = (f16)v.z; o[3] = (f16)v.w;
    d[i] = o;
  }
}

__global__ void bias_sum(const float* __restrict__ bih, const float* __restrict__ bhh,
                         float* __restrict__ b0, float* __restrict__ b1) {
  int i = blockIdx.x * blockDim.x + threadIdx.x;
  if (i < NG) { b0[i] = bih[i] + bhh[i]; b1[i] = bih[NG + i] + bhh[NG + i]; }
}

// xs[t][b][h] = (f16) emb[trg[b][t]][h], vectorized by 4
__global__ void embed_gather(const int* __restrict__ trg, const float* __restrict__ emb,
                             f16x4* __restrict__ xs) {
  int i = blockIdx.x * blockDim.x + threadIdx.x;   // over 8192*192
  if (i >= 8192 * 192) return;
  int h4 = i % 192;
  int mb = i / 192;                 // t*128 + b
  int b = mb & 127, t = mb >> 7;
  const float4* src = (const float4*)(emb + (size_t)trg[b * NT + t] * NH) + h4;
  float4 v = *src;
  f16x4 o; o[0] = (f16)v.x; o[1] = (f16)v.y; o[2] = (f16)v.z; o[3] = (f16)v.w;
  xs[i] = o;
}

// h0_init/h1_init from bert_table[src[b,0]]; zero c0,c1
__global__ void init_state(const int* __restrict__ src, const float* __restrict__ bert,
                           f16* __restrict__ h0i, f16* __restrict__ h1i,
                           float* __restrict__ c0, float* __restrict__ c1) {
  int i = blockIdx.x * blockDim.x + threadIdx.x;   // NB*NH
  if (i >= NB * NH) return;
  int h = i % NH, b = i / NH;
  float v = bert[(size_t)src[b * 32] * NH + h];
  h0i[i] = (f16)v; h1i[i] = (f16)v;
  c0[i] = 0.f; c1[i] = 0.f;
}

// ---------------- big GEMM (m97 structure): C = A(8192xK) @ B(NxK)^T + bias ----------------
// mode 0: f16 out, row-major MxN (G0)
// mode 1: f32 out, row m=(t*128+b) scattered to out[b*T*V + t*V + n] (projection)
__global__ __launch_bounds__(256) void gemm_bt(
    const f16* __restrict__ A, const f16* __restrict__ Bm,
    const float* __restrict__ bias,
    f16* __restrict__ Ch, float* __restrict__ Cf,
    int K, int N, int mode)
{
  __shared__ __align__(16) f16 As[128 * 32];
  __shared__ __align__(16) f16 Bs[128 * 32];
  int tid = threadIdx.x, w = tid >> 6, lane = tid & 63;
  int m0 = blockIdx.x * 128, n0 = blockIdx.y * 128;
  int wm = (w >> 1) * 64, wn = (w & 1) * 64;
  f32x4 acc[4][4];
#pragma unroll
  for (int i = 0; i < 4; i++)
#pragma unroll
    for (int j = 0; j < 4; j++) acc[i][j] = {0.f, 0.f, 0.f, 0.f};

  for (int k0 = 0; k0 < K; k0 += 32) {
    __syncthreads();
#pragma unroll
    for (int c = 0; c < 2; c++) {
      int f = c * 256 + tid;                       // 16B chunk id; row=f>>2, koff=(f&3)*8 halves
      gld_lds16(A + (size_t)(m0 + (f >> 2)) * K + k0 + (f & 3) * 8, As + (c * 256 + w * 64) * 8);
      gld_lds16(Bm + (size_t)(n0 + (f >> 2)) * K + k0 + (f & 3) * 8, Bs + (c * 256 + w * 64) * 8);
    }
    __syncthreads();
    f16x8 af[4], bf[4];
#pragma unroll
    for (int i = 0; i < 4; i++) {
      af[i] = *(const f16x8*)(As + (wm + i * 16 + (lane & 15)) * 32 + (lane >> 4) * 8);
      bf[i] = *(const f16x8*)(Bs + (wn + i * 16 + (lane & 15)) * 32 + (lane >> 4) * 8);
    }
#pragma unroll
    for (int i = 0; i < 4; i++)
#pragma unroll
      for (int j = 0; j < 4; j++)
        acc[i][j] = __builtin_amdgcn_mfma_f32_16x16x32_f16(af[i], bf[j], acc[i][j], 0, 0, 0);
  }

  int col = lane & 15, rowq = (lane >> 4) * 4;
  if (mode == 0) {
#pragma unroll
    for (int i = 0; i < 4; i++)
#pragma unroll
      for (int r = 0; r < 4; r++) {
        int m = m0 + wm + i * 16 + rowq + r;
#pragma unroll
        for (int j = 0; j < 4; j++) {
          int n = n0 + wn + j * 16 + col;
          Ch[(size_t)m * N + n] = (f16)(acc[i][j][r] + bias[n]);
        }
      }
  } else {
#pragma unroll
    for (int i = 0; i < 4; i++)
#pragma unroll
      for (int r = 0; r < 4; r++) {
        int m = m0 + wm + i * 16 + rowq + r;
        size_t rowp = (size_t)(m & 127) * ((size_t)NT * NV) + (size_t)(m >> 7) * NV;
#pragma unroll
        for (int j = 0; j < 4; j++) {
          int n = n0 + wn + j * 16 + col;
          Cf[rowp + n] = acc[i][j][r] + bias[n];
        }
      }
  }
}

// ---------------- LSTM phase kernel (wavefront over layers) ----------------
// blocks 0..47: layer0 step t=p (if p<64); blocks 48..95: layer1 step t=p-1 (if p>=1).
// Each block owns 16 hidden units (jb..jb+16); wave w computes gate w (i/f/g/o),
// a 128x16 strip, K accumulated via register-direct MFMA fragment loads (no LDS staging).
__global__ __launch_bounds__(256) void lstm_phase(
    int p,
    const f16* __restrict__ Whh0, const f16* __restrict__ Wih1, const f16* __restrict__ Whh1,
    const f16* __restrict__ G0, const float* __restrict__ b1,
    const f16* __restrict__ h0r, f16* __restrict__ h0w,
    const f16* __restrict__ h1r, f16* __restrict__ h1w,
    float* __restrict__ c0, float* __restrict__ c1,
    f16* __restrict__ ys)
{
  __shared__ float gl[4 * 128 * 16];
  int tid = threadIdx.x, w = tid >> 6, lane = tid & 63;
  int layer = blockIdx.x / 48;
  int jb = (blockIdx.x % 48) * 16;
  if (layer == 0 && p >= NT) return;
  if (layer == 1 && p < 1) return;
  int t = (layer == 0) ? p : (p - 1);

  f32x4 acc[8];
#pragma unroll
  for (int i = 0; i < 8; i++) acc[i] = {0.f, 0.f, 0.f, 0.f};

  int npass = (layer == 0) ? 1 : 2;
  for (int pass = 0; pass < npass; pass++) {
    const f16* hsrc = (pass == 0) ? h0r : h1r;            // layer0: h0(t-1); layer1: h0(t) then h1(t-1)
    const f16* Wm   = (layer == 0) ? Whh0 : ((pass == 0) ? Wih1 : Whh1);
    const f16* brow = Wm + (size_t)(w * NH + jb + (lane & 15)) * NH + (lane >> 4) * 8;
    const f16* arow = hsrc + (size_t)(lane & 15) * NH + (lane >> 4) * 8;
#pragma unroll 2
    for (int k0 = 0; k0 < NH; k0 += 32) {
      f16x8 bf = *(const f16x8*)(brow + k0);
#pragma unroll
      for (int mt = 0; mt < 8; mt++) {
        f16x8 af = *(const f16x8*)(arow + k0 + mt * 16 * NH);
        acc[mt] = __builtin_amdgcn_mfma_f32_16x16x32_f16(af, bf, acc[mt], 0, 0, 0);
      }
    }
  }

  int col = lane & 15, rowq = (lane >> 4) * 4;
  if (layer == 0) {
    const f16* g0t = G0 + (size_t)(t * NB) * NG;
#pragma unroll
    for (int mt = 0; mt < 8; mt++)
#pragma unroll
      for (int r = 0; r < 4; r++) {
        int m = mt * 16 + rowq + r;
        acc[mt][r] += (float)g0t[(size_t)m * NG + w * NH + jb + col];
      }
  }
#pragma unroll
  for (int mt = 0; mt < 8; mt++)
#pragma unroll
    for (int r = 0; r < 4; r++) {
      int m = mt * 16 + rowq + r;
      gl[(w * 128 + m) * 16 + col] = acc[mt][r];
    }
  __syncthreads();
  {
    int j = tid & 15, gj = jb + j;
    float* cst = (layer == 0) ? c0 : c1;
    f16* hw = (layer == 0) ? h0w : h1w;
#pragma unroll
    for (int mi = 0; mi < 8; mi++) {
      int m = (tid >> 4) * 8 + mi;
      float gi = gl[(0 * 128 + m) * 16 + j];
      float gf = gl[(1 * 128 + m) * 16 + j];
      float gg = gl[(2 * 128 + m) * 16 + j];
      float go = gl[(3 * 128 + m) * 16 + j];
      if (layer == 1) {
        gi += b1[0 * NH + gj]; gf += b1[1 * NH + gj];
        gg += b1[2 * NH + gj]; go += b1[3 * NH + gj];
      }
      float cp = cst[m * NH + gj];
      float cn = sigm(gf) * cp + sigm(gi) * tanh_fast(gg);
      float hn = sigm(go) * tanh_fast(cn);
      cst[m * NH + gj] = cn;
      hw[m * NH + gj] = (f16)hn;
      if (layer == 1) ys[((size_t)t * NB + m) * NH + gj] = (f16)hn;
    }
  }
}

// ---------------- launcher ----------------

extern "C" void kernel_launch(void* const* d_in, const int* in_sizes, int n_in,
                              void* d_out, int out_size, void* d_ws, size_t ws_size,
                              hipStream_t stream) {
  (void)in_sizes; (void)n_in; (void)out_size; (void)ws_size;
  const int*   src   = (const int*)d_in[0];
  const int*   trg   = (const int*)d_in[1];
  const float* bert  = (const float*)d_in[2];
  const float* emb   = (const float*)d_in[3];
  const float* W_ih  = (const float*)d_in[4];
  const float* W_hh  = (const float*)d_in[5];
  const float* b_ih  = (const float*)d_in[6];
  const float* b_hh  = (const float*)d_in[7];
  const float* W_out = (const float*)d_in[8];
  const float* b_out = (const float*)d_in[9];
  float* out = (float*)d_out;

  char* p = (char*)d_ws;
  auto alloc = [&](size_t bytes) { char* r = p; p += (bytes + 255) & ~(size_t)255; return r; };
  f16* WihH  = (f16*)alloc((size_t)2 * NG * NH * 2);   // both layers
  f16* WhhH  = (f16*)alloc((size_t)2 * NG * NH * 2);
  f16* WoutH = (f16*)alloc((size_t)NV * NH * 2);
  f16* xs    = (f16*)alloc((size_t)NT * NB * NH * 2);
  f16* G0    = (f16*)alloc((size_t)NT * NB * NG * 2);
  f16* ys    = (f16*)alloc((size_t)NT * NB * NH * 2);
  f16* h0A   = (f16*)alloc((size_t)NB * NH * 2);
  f16* h0B   = (f16*)alloc((size_t)NB * NH * 2);
  f16* h1A   = (f16*)alloc((size_t)NB * NH * 2);
  f16* h1B   = (f16*)alloc((size_t)NB * NH * 2);
  float* c0  = (float*)alloc((size_t)NB * NH * 4);
  float* c1  = (float*)alloc((size_t)NB * NH * 4);
  float* b0f = (float*)alloc(NG * 4);
  float* b1f = (float*)alloc(NG * 4);

  const f16* Wih1H = WihH + (size_t)NG * NH;
  const f16* Whh0H = WhhH;
  const f16* Whh1H = WhhH + (size_t)NG * NH;

  // prep
  {
    int n4 = 2 * NG * NH / 4;
    cvt4<<<(n4 + 255) / 256, 256, 0, stream>>>((const float4*)W_ih, (f16x4*)WihH, n4);
    cvt4<<<(n4 + 255) / 256, 256, 0, stream>>>((const float4*)W_hh, (f16x4*)WhhH, n4);
    int n4o = NV * NH / 4;
    cvt4<<<(n4o + 255) / 256, 256, 0, stream>>>((const float4*)W_out, (f16x4*)WoutH, n4o);
    bias_sum<<<(NG + 255) / 256, 256, 0, stream>>>(b_ih, b_hh, b0f, b1f);
    embed_gather<<<(8192 * 192 + 255) / 256, 256, 0, stream>>>(trg, emb, (f16x4*)xs);
    init_state<<<(NB * NH + 255) / 256, 256, 0, stream>>>(src, bert, h0B, h1A, c0, c1);
  }

  // G0 = xs @ W_ih0^T + (b_ih0 + b_hh0), f16 out (8192 x 3072)
  gemm_bt<<<dim3(64, NG / 128), 256, 0, stream>>>(xs, WihH, b0f, G0, nullptr, NH, NG, 0);

  // wavefront phases
  for (int ph = 0; ph < NT + 1; ph++) {
    const f16 *h0r, *h1r; f16 *h0w, *h1w;
    if (ph & 1) { h0r = h0A; h0w = h0B; h1r = h1A; h1w = h1B; }
    else        { h0r = h0B; h0w = h0A; h1r = h1B; h1w = h1A; }
    lstm_phase<<<96, 256, 0, stream>>>(ph, Whh0H, Wih1H, Whh1H, G0, b1f,
                                       h0r, h0w, h1r, h1w, c0, c1, ys);
  }

  // projection: out[b,t,v] = ys[t,b,:] @ W_out[v,:] + b_out[v]
  gemm_bt<<<dim3(64, NV / 128), 256, 0, stream>>>(ys, WoutH, b_out, nullptr, out, NH, NV, 1);
}